// Round 4
// baseline (211.992 us; speedup 1.0000x reference)
//
#include <hip/hip_runtime.h>
#include <hip/hip_bf16.h>
#include <math.h>

// Problem constants
#define Bb   4
#define Cc   128
#define Nn   4096          // 64*64 spatial
#define BN   (Bb * Nn)
#define NSLC 16            // partial slices (one per blockIdx.y)
#define HP   0.1f
#define EPSN 1e-10f
#define EPSM 0.001f

typedef __attribute__((ext_vector_type(8))) short short8;  // 8 bf16 = 4 VGPRs
typedef __attribute__((ext_vector_type(4))) float f32x4;   // MFMA accumulator

// Workspace layout (float offsets)
#define OFF_MEAN 0                 // [B*C]      = 512    (atomicAdd -> zeroed)
#define OFF_ACC  512               // [B]        = 4      (atomicAdd -> zeroed)
#define OFF_PMAX 1024              // [16][B*N]  = 262144 (fully overwritten)
#define OFF_SSP  263168            // [16][B*N]  = 262144 (fully overwritten)
#define OFF_FXN  525312            // bf16 [B*N*C] = 1048576 float slots
#define OFF_FYN  1573888           // bf16 [B*N*C]

// async global -> LDS, 16B per lane; LDS dest = wave-uniform base + lane*16
__device__ __forceinline__ void gload_lds16(const void* g, void* l)
{
    __builtin_amdgcn_global_load_lds(
        (const __attribute__((address_space(1))) unsigned int*)g,
        (__attribute__((address_space(3))) unsigned int*)l, 16, 0, 0);
}

// ---------------------------------------------------------------------------
// Kernel 1: per-(b,c) sums of feature_y over spatial dim (atomicAdd partials)
__global__ void k_mean(const float* __restrict__ fy, float* __restrict__ mean)
{
    int b = blockIdx.x >> 5;
    int chunk = blockIdx.x & 31;
    int c = threadIdx.x;           // 128 threads, one per channel
    const float* p = fy + ((size_t)b * Nn + (size_t)chunk * 128) * Cc + c;
    float s = 0.f;
    for (int n = 0; n < 128; ++n) s += p[(size_t)n * Cc];
    atomicAdd(&mean[b * Cc + c], s);
}

// ---------------------------------------------------------------------------
// Kernel 2: center by spatial mean of y, L2-normalize each (b,n) vector over C,
// emit bf16. 256 threads = 4 waves, one wave per (b,n) row.
__global__ void k_norm(const float* __restrict__ fx, const float* __restrict__ fy,
                       const float* __restrict__ mean,
                       __hip_bfloat16* __restrict__ fxn, __hip_bfloat16* __restrict__ fyn)
{
    int bn = blockIdx.x * 4 + (threadIdx.x >> 6);   // 0 .. B*N-1
    int b = bn >> 12;
    int l = threadIdx.x & 63;
    const float* px = fx + (size_t)bn * Cc;
    const float* py = fy + (size_t)bn * Cc;
    const float* mp = mean + b * Cc;

    float m0 = mp[l]      * (1.f / Nn);
    float m1 = mp[l + 64] * (1.f / Nn);
    float x0 = px[l] - m0, x1 = px[l + 64] - m1;
    float y0 = py[l] - m0, y1 = py[l + 64] - m1;
    float sx = x0 * x0 + x1 * x1;
    float sy = y0 * y0 + y1 * y1;
    #pragma unroll
    for (int o = 32; o > 0; o >>= 1) {
        sx += __shfl_xor(sx, o);
        sy += __shfl_xor(sy, o);
    }
    float ix = 1.f / (sqrtf(sx) + EPSN);
    float iy = 1.f / (sqrtf(sy) + EPSN);
    fxn[(size_t)bn * Cc + l]      = __float2bfloat16(x0 * ix);
    fxn[(size_t)bn * Cc + l + 64] = __float2bfloat16(x1 * ix);
    fyn[(size_t)bn * Cc + l]      = __float2bfloat16(y0 * iy);
    fyn[(size_t)bn * Cc + l + 64] = __float2bfloat16(y1 * iy);
}

// ---------------------------------------------------------------------------
// MFMA core: per batch, S = X · Y^T  (M=N=4096, K=C=128).
// Block = 128-row strip of A (staged once, async DMA, XOR-swizzled LDS) x
// 2 m-tiles of B (direct from global, L2-hot).
// R4 = R1 structure at the CORRECT register budget:
//  - __launch_bounds__(256,3): unified VGPR+AGPR cap 170. Live set ≈
//    acc 64 (AGPR) + bb 16 + a 16 + vpart 16 + addr/misc ≈ 164. Fits.
//    (R2 cap=128 and R3 ping-pong ≈180 both spilled: WRITE_SIZE 240-283 MB.)
//  - per-mt partials fold into vpart[4][4] regs; ONE epilogue per block
//    (baseline had two, each with 2 barriers + 128-thread reduce).
//  - sred aliases sA (A dead by epilogue). LDS 33.8 KB.
//  - pmax/ssp: 16 slices (was 32) -> half the partial traffic.
// PASS 1: per-row per-block max of dot -> pmax[my][b*N+row]
// PASS 2: prologue reduces pmax -> affine exp coeffs in LDS;
//         per-row per-block sum exp(fma(dot,c1,c0)) -> ssp[my][...]
template <int PASS>
__global__ __launch_bounds__(256, 3) void k_gemm(
    const ushort* __restrict__ fxn, const ushort* __restrict__ fyn,
    float* __restrict__ pmax, float* __restrict__ ssp)
{
    // union: sA (32 KB, staging + fragment reads) then sred (18 KB, epilogue)
    __shared__ __align__(16) char smem[128 * 128 * 2];
    ushort* sA   = (ushort*)smem;
    float*  sred = (float*)smem;
    __shared__ float sctv[256];         // 1 KB {c0,c1} per row

    const int tid  = threadIdx.x;
    const int lane = tid & 63;
    const int w    = tid >> 6;
    const int n0   = blockIdx.x * 128;
    const int my   = blockIdx.y;          // 0..15 -> m-tiles 2my, 2my+1
    const int b    = blockIdx.z;

    const ushort* gA = fxn + (size_t)b * Nn * Cc;
    const ushort* gB = fyn + (size_t)b * Nn * Cc;

    // PASS 2 prologue: 16 max-partials -> {c0,c1}: arg(dot) = dot*t + (d-1)*t,
    // d = 1 - maxdot, t = 1/(HP*(d+eps)).
    if (PASS == 2 && tid < 128) {
        int row = b * Nn + n0 + tid;
        float g = -1e30f;
        #pragma unroll
        for (int z = 0; z < NSLC; ++z) g = fmaxf(g, pmax[(size_t)z * BN + row]);
        float d = 1.f - g;
        float t = 1.f / (HP * (d + EPSM));
        ((float2*)sctv)[tid] = (float2){(d - 1.f) * t, t};
    }

    // Stage A strip once (async DMA; chunk16 c of row r at slot c^(r&15)).
    #pragma unroll
    for (int inst = 0; inst < 8; ++inst) {
        int L0 = w * 512 + inst * 64;
        int L  = L0 + lane;
        int r = L >> 4, s = L & 15;
        int c = s ^ (r & 15);
        gload_lds16(gA + (size_t)(n0 + r) * Cc + c * 8, &sA[L0 * 8]);
    }
    __syncthreads();   // drains DMA; sA + sctv visible

    const int l15 = lane & 15, q = lane >> 4;
    const int wy = w >> 1, wx = w & 1;     // wave's 64x64 quadrant

    // cross-mt partials: PASS1 max, PASS2 exp-sum
    float vpart[4][4];
    #pragma unroll
    for (int i = 0; i < 4; ++i)
        #pragma unroll
        for (int r = 0; r < 4; ++r)
            vpart[i][r] = (PASS == 1) ? -1e30f : 0.f;

    #pragma unroll 1
    for (int mt = 0; mt < 2; ++mt) {
        const int m0 = (my * 2 + mt) * 128;
        // Per-lane B base: row m0 + wx*64 + l15, col chunk q*8.
        const ushort* pB = gB + (size_t)(m0 + wx * 64 + l15) * Cc + q * 8;

        f32x4 acc[4][4];
        #pragma unroll
        for (int i = 0; i < 4; ++i)
            #pragma unroll
            for (int j = 0; j < 4; ++j)
                acc[i][j] = (f32x4){0.f, 0.f, 0.f, 0.f};

        #pragma unroll
        for (int kt = 0; kt < 4; ++kt) {
            short8 a[4], bb[4];
            const int sw = ((kt * 4 + q) ^ l15) * 8;   // swizzled A chunk
            #pragma unroll
            for (int j = 0; j < 4; ++j)
                bb[j] = *(const short8*)(pB + (size_t)j * 16 * Cc + kt * 32);
            #pragma unroll
            for (int i = 0; i < 4; ++i)
                a[i] = *(const short8*)&sA[(wy * 64 + i * 16 + l15) * 128 + sw];
            #pragma unroll
            for (int i = 0; i < 4; ++i)
                #pragma unroll
                for (int j = 0; j < 4; ++j)
                    acc[i][j] = __builtin_amdgcn_mfma_f32_16x16x32_bf16(
                        a[i], bb[j], acc[i][j], 0, 0, 0);
        }

        // Fold this m-tile into vpart (regs only; no LDS, no barrier).
        // C/D layout: col = lane&15, row = (lane>>4)*4 + reg  [m89-verified]
        #pragma unroll
        for (int i = 0; i < 4; ++i)
            #pragma unroll
            for (int r = 0; r < 4; ++r) {
                if (PASS == 1) {
                    float v = fmaxf(fmaxf(acc[i][0][r], acc[i][1][r]),
                                    fmaxf(acc[i][2][r], acc[i][3][r]));
                    vpart[i][r] = fmaxf(vpart[i][r], v);
                } else {
                    int row = wy * 64 + i * 16 + q * 4 + r;
                    float2 cc = ((const float2*)sctv)[row];   // {c0, c1}
                    float v = __expf(fmaf(acc[i][0][r], cc.y, cc.x))
                            + __expf(fmaf(acc[i][1][r], cc.y, cc.x))
                            + __expf(fmaf(acc[i][2][r], cc.y, cc.x))
                            + __expf(fmaf(acc[i][3][r], cc.y, cc.x));  // args <= ~0
                    vpart[i][r] += v;
                }
            }
    }

    // Single epilogue: all waves done reading sA -> reuse as sred.
    __syncthreads();
    #pragma unroll
    for (int i = 0; i < 4; ++i)
        #pragma unroll
        for (int r = 0; r < 4; ++r) {
            int row = wy * 64 + i * 16 + q * 4 + r;
            sred[row * 36 + wx * 16 + l15] = vpart[i][r];
        }
    __syncthreads();   // sred complete
    if (tid < 128) {
        const float4* p = (const float4*)&sred[tid * 36];
        float4 v0 = p[0], v1 = p[1], v2 = p[2], v3 = p[3];
        float4 v4 = p[4], v5 = p[5], v6 = p[6], v7 = p[7];
        float v;
        if (PASS == 1) {
            float4 m01 = (float4){fmaxf(v0.x, v1.x), fmaxf(v0.y, v1.y),
                                  fmaxf(v0.z, v1.z), fmaxf(v0.w, v1.w)};
            float4 m23 = (float4){fmaxf(v2.x, v3.x), fmaxf(v2.y, v3.y),
                                  fmaxf(v2.z, v3.z), fmaxf(v2.w, v3.w)};
            float4 m45 = (float4){fmaxf(v4.x, v5.x), fmaxf(v4.y, v5.y),
                                  fmaxf(v4.z, v5.z), fmaxf(v4.w, v5.w)};
            float4 m67 = (float4){fmaxf(v6.x, v7.x), fmaxf(v6.y, v7.y),
                                  fmaxf(v6.z, v7.z), fmaxf(v6.w, v7.w)};
            float4 ma = (float4){fmaxf(m01.x, m23.x), fmaxf(m01.y, m23.y),
                                 fmaxf(m01.z, m23.z), fmaxf(m01.w, m23.w)};
            float4 mb = (float4){fmaxf(m45.x, m67.x), fmaxf(m45.y, m67.y),
                                 fmaxf(m45.z, m67.z), fmaxf(m45.w, m67.w)};
            v = fmaxf(fmaxf(fmaxf(ma.x, mb.x), fmaxf(ma.y, mb.y)),
                      fmaxf(fmaxf(ma.z, mb.z), fmaxf(ma.w, mb.w)));
        } else {
            float4 s01 = (float4){v0.x + v1.x, v0.y + v1.y,
                                  v0.z + v1.z, v0.w + v1.w};
            float4 s23 = (float4){v2.x + v3.x, v2.y + v3.y,
                                  v2.z + v3.z, v2.w + v3.w};
            float4 s45 = (float4){v4.x + v5.x, v4.y + v5.y,
                                  v4.z + v5.z, v4.w + v5.w};
            float4 s67 = (float4){v6.x + v7.x, v6.y + v7.y,
                                  v6.z + v7.z, v6.w + v7.w};
            v = (s01.x + s23.x) + (s01.y + s23.y)
              + (s01.z + s23.z) + (s01.w + s23.w)
              + (s45.x + s67.x) + (s45.y + s67.y)
              + (s45.z + s67.z) + (s45.w + s67.w);
        }
        float* dst = (PASS == 1) ? pmax : ssp;
        dst[(size_t)my * BN + b * Nn + n0 + tid] = v;
    }
}

// ---------------------------------------------------------------------------
// Stage 1 of final reduction: per-row 1/s, block-sum, atomicAdd per batch.
__global__ void k_partial(const float* __restrict__ ssp, float* __restrict__ acc)
{
    int i = blockIdx.x * 256 + threadIdx.x;   // 0 .. B*N-1 (block spans one batch)
    float t = 0.f;
    #pragma unroll
    for (int z = 0; z < NSLC; ++z) t += ssp[(size_t)z * BN + i];
    float s = 1.f / t;
    #pragma unroll
    for (int o = 32; o > 0; o >>= 1) s += __shfl_xor(s, o);
    __shared__ float red[4];
    if ((threadIdx.x & 63) == 0) red[threadIdx.x >> 6] = s;
    __syncthreads();
    if (threadIdx.x == 0)
        atomicAdd(&acc[i >> 12], red[0] + red[1] + red[2] + red[3]);
}

__global__ void k_out(const float* __restrict__ acc, float* __restrict__ out)
{
    int b = threadIdx.x;
    if (b < Bb) out[b] = -logf(acc[b] * (1.f / Nn));
}

// ---------------------------------------------------------------------------
extern "C" void kernel_launch(void* const* d_in, const int* in_sizes, int n_in,
                              void* d_out, int out_size, void* d_ws, size_t ws_size,
                              hipStream_t stream)
{
    const float* fx = (const float*)d_in[0];
    const float* fy = (const float*)d_in[1];
    float* out = (float*)d_out;
    float* ws  = (float*)d_ws;

    float* mean = ws + OFF_MEAN;
    float* acc  = ws + OFF_ACC;
    float* pmax = ws + OFF_PMAX;
    float* ssp  = ws + OFF_SSP;
    __hip_bfloat16* fxn = (__hip_bfloat16*)(ws + OFF_FXN);
    __hip_bfloat16* fyn = (__hip_bfloat16*)(ws + OFF_FYN);

    // zero the atomicAdd accumulators (mean @0..511, acc @512..515)
    hipMemsetAsync(ws, 0, 516 * sizeof(float), stream);

    k_mean<<<dim3(Bb * 32), dim3(128), 0, stream>>>(fy, mean);
    k_norm<<<dim3(Bb * Nn / 4), dim3(256), 0, stream>>>(fx, fy, mean, fxn, fyn);

    dim3 gg(32, 16, Bb);   // 2048 blocks, 2 m-tiles each; 3 blocks/CU
    k_gemm<1><<<gg, dim3(256), 0, stream>>>((const ushort*)fxn, (const ushort*)fyn,
                                            pmax, nullptr);
    k_gemm<2><<<gg, dim3(256), 0, stream>>>((const ushort*)fxn, (const ushort*)fyn,
                                            pmax, ssp);
    k_partial<<<dim3(BN / 256), dim3(256), 0, stream>>>(ssp, acc);
    k_out<<<dim3(1), dim3(64), 0, stream>>>(acc, out);
}

// Round 5
// 153.190 us; speedup vs baseline: 1.3839x; 1.3839x over previous
//
#include <hip/hip_runtime.h>
#include <hip/hip_bf16.h>
#include <math.h>

// Problem constants
#define Bb   4
#define Cc   128
#define Nn   4096          // 64*64 spatial
#define BN   (Bb * Nn)
#define NSLC 16            // partial slices (one per blockIdx.y)
#define HP   0.1f
#define EPSN 1e-10f
#define EPSM 0.001f

typedef __attribute__((ext_vector_type(8))) short short8;  // 8 bf16 = 4 VGPRs
typedef __attribute__((ext_vector_type(4))) float f32x4;   // MFMA accumulator

// Workspace layout (float offsets)
#define OFF_MEAN 0                 // [B*C]      = 512    (atomicAdd -> zeroed)
#define OFF_ACC  512               // [B]        = 4      (atomicAdd -> zeroed)
#define OFF_PMAX 1024              // [16][B*N]  = 262144 (fully overwritten)
#define OFF_SSP  263168            // [16][B*N]  = 262144 (fully overwritten)
#define OFF_FXN  525312            // bf16 [B*N*C] = 1048576 float slots
#define OFF_FYN  1573888           // bf16 [B*N*C]

// async global -> LDS, 16B per lane; LDS dest = wave-uniform base + lane*16
__device__ __forceinline__ void gload_lds16(const void* g, void* l)
{
    __builtin_amdgcn_global_load_lds(
        (const __attribute__((address_space(1))) unsigned int*)g,
        (__attribute__((address_space(3))) unsigned int*)l, 16, 0, 0);
}

// ---------------------------------------------------------------------------
// Kernel 1: per-(b,c) sums of feature_y over spatial dim (atomicAdd partials)
__global__ void k_mean(const float* __restrict__ fy, float* __restrict__ mean)
{
    int b = blockIdx.x >> 5;
    int chunk = blockIdx.x & 31;
    int c = threadIdx.x;           // 128 threads, one per channel
    const float* p = fy + ((size_t)b * Nn + (size_t)chunk * 128) * Cc + c;
    float s = 0.f;
    for (int n = 0; n < 128; ++n) s += p[(size_t)n * Cc];
    atomicAdd(&mean[b * Cc + c], s);
}

// ---------------------------------------------------------------------------
// Kernel 2: center by spatial mean of y, L2-normalize each (b,n) vector over C,
// emit bf16. 256 threads = 4 waves, one wave per (b,n) row.
__global__ void k_norm(const float* __restrict__ fx, const float* __restrict__ fy,
                       const float* __restrict__ mean,
                       __hip_bfloat16* __restrict__ fxn, __hip_bfloat16* __restrict__ fyn)
{
    int bn = blockIdx.x * 4 + (threadIdx.x >> 6);   // 0 .. B*N-1
    int b = bn >> 12;
    int l = threadIdx.x & 63;
    const float* px = fx + (size_t)bn * Cc;
    const float* py = fy + (size_t)bn * Cc;
    const float* mp = mean + b * Cc;

    float m0 = mp[l]      * (1.f / Nn);
    float m1 = mp[l + 64] * (1.f / Nn);
    float x0 = px[l] - m0, x1 = px[l + 64] - m1;
    float y0 = py[l] - m0, y1 = py[l + 64] - m1;
    float sx = x0 * x0 + x1 * x1;
    float sy = y0 * y0 + y1 * y1;
    #pragma unroll
    for (int o = 32; o > 0; o >>= 1) {
        sx += __shfl_xor(sx, o);
        sy += __shfl_xor(sy, o);
    }
    float ix = 1.f / (sqrtf(sx) + EPSN);
    float iy = 1.f / (sqrtf(sy) + EPSN);
    fxn[(size_t)bn * Cc + l]      = __float2bfloat16(x0 * ix);
    fxn[(size_t)bn * Cc + l + 64] = __float2bfloat16(x1 * ix);
    fyn[(size_t)bn * Cc + l]      = __float2bfloat16(y0 * iy);
    fyn[(size_t)bn * Cc + l + 64] = __float2bfloat16(y1 * iy);
}

// ---------------------------------------------------------------------------
// MFMA core: per batch, S = X · Y^T  (M=N=4096, K=C=128).
// Block = 128-row strip of A (staged once, async DMA, XOR-swizzled LDS) x
// 2 m-tiles of B (direct from global, L2-hot).
// R5 = R3 structure at __launch_bounds__(256,2): unified cap 256.
//   Live set: acc 64 + bbA/bbB 32 + a 16 + vpart 16 + addr ~30 + temps ≈ 180.
//   R2 (cap 128), R3/R4 (cap ~168) ALL spilled (WRITE_SIZE 138-283 MB,
//   scratch round-trip = whole dispatch). Register headroom is the
//   precondition for every structural improvement -> trade occupancy
//   (3 -> 2 blocks/CU) for it; depth-1 B ping-pong supplies the ILP that
//   the lost wave supplied as TLP.
//  - mt x kt flattened to 8 steps; B prefetch ping-pongs bbA/bbB (static
//    indexing, rule #20); first B load issued BEFORE __syncthreads so it
//    rides under the A-DMA drain; main loop has ZERO barriers.
//  - per-mt partials fold into vpart[4][4] regs; ONE epilogue per block.
//  - sred aliases sA (A dead by epilogue). LDS 33.8 KB.
// PASS 1: per-row per-block max of dot -> pmax[my][b*N+row]
// PASS 2: prologue reduces pmax -> affine exp coeffs in LDS;
//         per-row per-block sum exp(fma(dot,c1,c0)) -> ssp[my][...]
template <int PASS>
__global__ __launch_bounds__(256, 2) void k_gemm(
    const ushort* __restrict__ fxn, const ushort* __restrict__ fyn,
    float* __restrict__ pmax, float* __restrict__ ssp)
{
    // union: sA (32 KB, staging + fragment reads) then sred (18 KB, epilogue)
    __shared__ __align__(16) char smem[128 * 128 * 2];
    ushort* sA   = (ushort*)smem;
    float*  sred = (float*)smem;
    __shared__ float sctv[256];         // 1 KB {c0,c1} per row

    const int tid  = threadIdx.x;
    const int lane = tid & 63;
    const int w    = tid >> 6;
    const int n0   = blockIdx.x * 128;
    const int my   = blockIdx.y;          // 0..15 -> m-tiles 2my, 2my+1
    const int b    = blockIdx.z;

    const ushort* gA = fxn + (size_t)b * Nn * Cc;
    const ushort* gB = fyn + (size_t)b * Nn * Cc;

    // PASS 2 prologue: 16 max-partials -> {c0,c1}: arg(dot) = dot*t + (d-1)*t,
    // d = 1 - maxdot, t = 1/(HP*(d+eps)).
    if (PASS == 2 && tid < 128) {
        int row = b * Nn + n0 + tid;
        float g = -1e30f;
        #pragma unroll
        for (int z = 0; z < NSLC; ++z) g = fmaxf(g, pmax[(size_t)z * BN + row]);
        float d = 1.f - g;
        float t = 1.f / (HP * (d + EPSM));
        ((float2*)sctv)[tid] = (float2){(d - 1.f) * t, t};
    }

    // Stage A strip once (async DMA; chunk16 c of row r at slot c^(r&15)).
    #pragma unroll
    for (int inst = 0; inst < 8; ++inst) {
        int L0 = w * 512 + inst * 64;
        int L  = L0 + lane;
        int r = L >> 4, s = L & 15;
        int c = s ^ (r & 15);
        gload_lds16(gA + (size_t)(n0 + r) * Cc + c * 8, &sA[L0 * 8]);
    }

    const int l15 = lane & 15, q = lane >> 4;
    const int wy = w >> 1, wx = w & 1;     // wave's 64x64 quadrant

    // Per-lane B bases for the two m-tiles.
    const ushort* pB0 = gB + (size_t)((my * 2) * 128 + wx * 64 + l15) * Cc + q * 8;
    const ushort* pB1 = pB0 + (size_t)128 * Cc;

#define LOADB(buf, base, kt)                                                   \
    {                                                                          \
        buf[0] = *(const short8*)((base) + (size_t)0 * 16 * Cc + (kt) * 32);   \
        buf[1] = *(const short8*)((base) + (size_t)1 * 16 * Cc + (kt) * 32);   \
        buf[2] = *(const short8*)((base) + (size_t)2 * 16 * Cc + (kt) * 32);   \
        buf[3] = *(const short8*)((base) + (size_t)3 * 16 * Cc + (kt) * 32);   \
    }

#define DOKT(kt, buf)                                                          \
    {                                                                          \
        const int sw = (((kt) * 4 + q) ^ l15) * 8;                             \
        short8 a0 = *(const short8*)&sA[(wy * 64 +  0 + l15) * 128 + sw];      \
        short8 a1 = *(const short8*)&sA[(wy * 64 + 16 + l15) * 128 + sw];      \
        short8 a2 = *(const short8*)&sA[(wy * 64 + 32 + l15) * 128 + sw];      \
        short8 a3 = *(const short8*)&sA[(wy * 64 + 48 + l15) * 128 + sw];      \
        acc[0][0] = __builtin_amdgcn_mfma_f32_16x16x32_bf16(a0, buf[0], acc[0][0], 0, 0, 0); \
        acc[0][1] = __builtin_amdgcn_mfma_f32_16x16x32_bf16(a0, buf[1], acc[0][1], 0, 0, 0); \
        acc[0][2] = __builtin_amdgcn_mfma_f32_16x16x32_bf16(a0, buf[2], acc[0][2], 0, 0, 0); \
        acc[0][3] = __builtin_amdgcn_mfma_f32_16x16x32_bf16(a0, buf[3], acc[0][3], 0, 0, 0); \
        acc[1][0] = __builtin_amdgcn_mfma_f32_16x16x32_bf16(a1, buf[0], acc[1][0], 0, 0, 0); \
        acc[1][1] = __builtin_amdgcn_mfma_f32_16x16x32_bf16(a1, buf[1], acc[1][1], 0, 0, 0); \
        acc[1][2] = __builtin_amdgcn_mfma_f32_16x16x32_bf16(a1, buf[2], acc[1][2], 0, 0, 0); \
        acc[1][3] = __builtin_amdgcn_mfma_f32_16x16x32_bf16(a1, buf[3], acc[1][3], 0, 0, 0); \
        acc[2][0] = __builtin_amdgcn_mfma_f32_16x16x32_bf16(a2, buf[0], acc[2][0], 0, 0, 0); \
        acc[2][1] = __builtin_amdgcn_mfma_f32_16x16x32_bf16(a2, buf[1], acc[2][1], 0, 0, 0); \
        acc[2][2] = __builtin_amdgcn_mfma_f32_16x16x32_bf16(a2, buf[2], acc[2][2], 0, 0, 0); \
        acc[2][3] = __builtin_amdgcn_mfma_f32_16x16x32_bf16(a2, buf[3], acc[2][3], 0, 0, 0); \
        acc[3][0] = __builtin_amdgcn_mfma_f32_16x16x32_bf16(a3, buf[0], acc[3][0], 0, 0, 0); \
        acc[3][1] = __builtin_amdgcn_mfma_f32_16x16x32_bf16(a3, buf[1], acc[3][1], 0, 0, 0); \
        acc[3][2] = __builtin_amdgcn_mfma_f32_16x16x32_bf16(a3, buf[2], acc[3][2], 0, 0, 0); \
        acc[3][3] = __builtin_amdgcn_mfma_f32_16x16x32_bf16(a3, buf[3], acc[3][3], 0, 0, 0); \
    }

// Fold current acc into vpart (regs only), then reset acc.
// C/D layout: col = lane&15, row = (lane>>4)*4 + reg  [m89-verified]
#define FOLD()                                                                 \
    {                                                                          \
        _Pragma("unroll")                                                      \
        for (int i = 0; i < 4; ++i) {                                          \
            _Pragma("unroll")                                                  \
            for (int r = 0; r < 4; ++r) {                                      \
                if (PASS == 1) {                                               \
                    float v = fmaxf(fmaxf(acc[i][0][r], acc[i][1][r]),         \
                                    fmaxf(acc[i][2][r], acc[i][3][r]));        \
                    vpart[i][r] = fmaxf(vpart[i][r], v);                       \
                } else {                                                       \
                    int row = wy * 64 + i * 16 + q * 4 + r;                    \
                    float2 cc = ((const float2*)sctv)[row];                    \
                    vpart[i][r] += __expf(fmaf(acc[i][0][r], cc.y, cc.x))      \
                                 + __expf(fmaf(acc[i][1][r], cc.y, cc.x))      \
                                 + __expf(fmaf(acc[i][2][r], cc.y, cc.x))      \
                                 + __expf(fmaf(acc[i][3][r], cc.y, cc.x));     \
                }                                                              \
            }                                                                  \
            _Pragma("unroll")                                                  \
            for (int j = 0; j < 4; ++j)                                        \
                acc[i][j] = (f32x4){0.f, 0.f, 0.f, 0.f};                       \
        }                                                                      \
    }

    short8 bbA[4], bbB[4];
    LOADB(bbA, pB0, 0);        // rides under the A-DMA drain
    __syncthreads();           // drains DMA (and bbA); sA + sctv visible

    f32x4 acc[4][4];
    #pragma unroll
    for (int i = 0; i < 4; ++i)
        #pragma unroll
        for (int j = 0; j < 4; ++j)
            acc[i][j] = (f32x4){0.f, 0.f, 0.f, 0.f};

    float vpart[4][4];
    #pragma unroll
    for (int i = 0; i < 4; ++i)
        #pragma unroll
        for (int r = 0; r < 4; ++r)
            vpart[i][r] = (PASS == 1) ? -1e30f : 0.f;

    // 8 flattened steps, depth-1 B prefetch (static ping-pong).
    LOADB(bbB, pB0, 1); DOKT(0, bbA);
    LOADB(bbA, pB0, 2); DOKT(1, bbB);
    LOADB(bbB, pB0, 3); DOKT(2, bbA);
    LOADB(bbA, pB1, 0); DOKT(3, bbB);
    FOLD();                                  // m-tile 0 -> vpart
    LOADB(bbB, pB1, 1); DOKT(0, bbA);
    LOADB(bbA, pB1, 2); DOKT(1, bbB);
    LOADB(bbB, pB1, 3); DOKT(2, bbA);
    DOKT(3, bbB);
    FOLD();                                  // m-tile 1 -> vpart

#undef LOADB
#undef DOKT
#undef FOLD

    // Single epilogue: all waves done reading sA -> reuse as sred.
    __syncthreads();
    #pragma unroll
    for (int i = 0; i < 4; ++i)
        #pragma unroll
        for (int r = 0; r < 4; ++r) {
            int row = wy * 64 + i * 16 + q * 4 + r;
            sred[row * 36 + wx * 16 + l15] = vpart[i][r];
        }
    __syncthreads();   // sred complete
    if (tid < 128) {
        const float4* p = (const float4*)&sred[tid * 36];
        float4 v0 = p[0], v1 = p[1], v2 = p[2], v3 = p[3];
        float4 v4 = p[4], v5 = p[5], v6 = p[6], v7 = p[7];
        float v;
        if (PASS == 1) {
            float4 m01 = (float4){fmaxf(v0.x, v1.x), fmaxf(v0.y, v1.y),
                                  fmaxf(v0.z, v1.z), fmaxf(v0.w, v1.w)};
            float4 m23 = (float4){fmaxf(v2.x, v3.x), fmaxf(v2.y, v3.y),
                                  fmaxf(v2.z, v3.z), fmaxf(v2.w, v3.w)};
            float4 m45 = (float4){fmaxf(v4.x, v5.x), fmaxf(v4.y, v5.y),
                                  fmaxf(v4.z, v5.z), fmaxf(v4.w, v5.w)};
            float4 m67 = (float4){fmaxf(v6.x, v7.x), fmaxf(v6.y, v7.y),
                                  fmaxf(v6.z, v7.z), fmaxf(v6.w, v7.w)};
            float4 ma = (float4){fmaxf(m01.x, m23.x), fmaxf(m01.y, m23.y),
                                 fmaxf(m01.z, m23.z), fmaxf(m01.w, m23.w)};
            float4 mb = (float4){fmaxf(m45.x, m67.x), fmaxf(m45.y, m67.y),
                                 fmaxf(m45.z, m67.z), fmaxf(m45.w, m67.w)};
            v = fmaxf(fmaxf(fmaxf(ma.x, mb.x), fmaxf(ma.y, mb.y)),
                      fmaxf(fmaxf(ma.z, mb.z), fmaxf(ma.w, mb.w)));
        } else {
            float4 s01 = (float4){v0.x + v1.x, v0.y + v1.y,
                                  v0.z + v1.z, v0.w + v1.w};
            float4 s23 = (float4){v2.x + v3.x, v2.y + v3.y,
                                  v2.z + v3.z, v2.w + v3.w};
            float4 s45 = (float4){v4.x + v5.x, v4.y + v5.y,
                                  v4.z + v5.z, v4.w + v5.w};
            float4 s67 = (float4){v6.x + v7.x, v6.y + v7.y,
                                  v6.z + v7.z, v6.w + v7.w};
            v = (s01.x + s23.x) + (s01.y + s23.y)
              + (s01.z + s23.z) + (s01.w + s23.w)
              + (s45.x + s67.x) + (s45.y + s67.y)
              + (s45.z + s67.z) + (s45.w + s67.w);
        }
        float* dst = (PASS == 1) ? pmax : ssp;
        dst[(size_t)my * BN + b * Nn + n0 + tid] = v;
    }
}

// ---------------------------------------------------------------------------
// Stage 1 of final reduction: per-row 1/s, block-sum, atomicAdd per batch.
__global__ void k_partial(const float* __restrict__ ssp, float* __restrict__ acc)
{
    int i = blockIdx.x * 256 + threadIdx.x;   // 0 .. B*N-1 (block spans one batch)
    float t = 0.f;
    #pragma unroll
    for (int z = 0; z < NSLC; ++z) t += ssp[(size_t)z * BN + i];
    float s = 1.f / t;
    #pragma unroll
    for (int o = 32; o > 0; o >>= 1) s += __shfl_xor(s, o);
    __shared__ float red[4];
    if ((threadIdx.x & 63) == 0) red[threadIdx.x >> 6] = s;
    __syncthreads();
    if (threadIdx.x == 0)
        atomicAdd(&acc[i >> 12], red[0] + red[1] + red[2] + red[3]);
}

__global__ void k_out(const float* __restrict__ acc, float* __restrict__ out)
{
    int b = threadIdx.x;
    if (b < Bb) out[b] = -logf(acc[b] * (1.f / Nn));
}

// ---------------------------------------------------------------------------
extern "C" void kernel_launch(void* const* d_in, const int* in_sizes, int n_in,
                              void* d_out, int out_size, void* d_ws, size_t ws_size,
                              hipStream_t stream)
{
    const float* fx = (const float*)d_in[0];
    const float* fy = (const float*)d_in[1];
    float* out = (float*)d_out;
    float* ws  = (float*)d_ws;

    float* mean = ws + OFF_MEAN;
    float* acc  = ws + OFF_ACC;
    float* pmax = ws + OFF_PMAX;
    float* ssp  = ws + OFF_SSP;
    __hip_bfloat16* fxn = (__hip_bfloat16*)(ws + OFF_FXN);
    __hip_bfloat16* fyn = (__hip_bfloat16*)(ws + OFF_FYN);

    // zero the atomicAdd accumulators (mean @0..511, acc @512..515)
    hipMemsetAsync(ws, 0, 516 * sizeof(float), stream);

    k_mean<<<dim3(Bb * 32), dim3(128), 0, stream>>>(fy, mean);
    k_norm<<<dim3(Bb * Nn / 4), dim3(256), 0, stream>>>(fx, fy, mean, fxn, fyn);

    dim3 gg(32, 16, Bb);   // 2048 blocks, 2 m-tiles each; 2 blocks/CU
    k_gemm<1><<<gg, dim3(256), 0, stream>>>((const ushort*)fxn, (const ushort*)fyn,
                                            pmax, nullptr);
    k_gemm<2><<<gg, dim3(256), 0, stream>>>((const ushort*)fxn, (const ushort*)fyn,
                                            pmax, ssp);
    k_partial<<<dim3(BN / 256), dim3(256), 0, stream>>>(ssp, acc);
    k_out<<<dim3(1), dim3(64), 0, stream>>>(acc, out);
}

// Round 7
// 143.957 us; speedup vs baseline: 1.4726x; 1.0641x over previous
//
#include <hip/hip_runtime.h>
#include <hip/hip_bf16.h>
#include <math.h>

// Problem constants
#define Bb   4
#define Cc   128
#define Nn   4096          // 64*64 spatial
#define BN   (Bb * Nn)
#define NSLC 4             // partial slices (one per my)
#define HP   0.1f
#define EPSN 1e-10f
#define EPSM 0.001f

typedef __attribute__((ext_vector_type(8))) short short8;  // 8 bf16 = 4 VGPRs
typedef __attribute__((ext_vector_type(4))) float f32x4;   // MFMA accumulator

// Workspace layout (float offsets) — unchanged from prior rounds (ws already sized)
#define OFF_MEAN 0                 // [B*C]      = 512    (atomicAdd -> zeroed)
#define OFF_ACC  512               // [B]        = 4      (atomicAdd -> zeroed)
#define OFF_PMAX 1024              // [4][B*N]   = 65536  (fully overwritten)
#define OFF_SSP  263168            // [4][B*N]   = 65536  (fully overwritten)
#define OFF_FXN  525312            // bf16 [B*N*C] = 1048576 float slots
#define OFF_FYN  1573888           // bf16 [B*N*C]

// async global -> LDS, 16B per lane; LDS dest = wave-uniform base + lane*16
__device__ __forceinline__ void gload_lds16(const void* g, void* l)
{
    __builtin_amdgcn_global_load_lds(
        (const __attribute__((address_space(1))) unsigned int*)g,
        (__attribute__((address_space(3))) unsigned int*)l, 16, 0, 0);
}

// ---------------------------------------------------------------------------
// Kernel 1: per-(b,c) sums of feature_y over spatial dim (atomicAdd partials)
__global__ void k_mean(const float* __restrict__ fy, float* __restrict__ mean)
{
    int b = blockIdx.x >> 5;
    int chunk = blockIdx.x & 31;
    int c = threadIdx.x;           // 128 threads, one per channel
    const float* p = fy + ((size_t)b * Nn + (size_t)chunk * 128) * Cc + c;
    float s = 0.f;
    for (int n = 0; n < 128; ++n) s += p[(size_t)n * Cc];
    atomicAdd(&mean[b * Cc + c], s);
}

// ---------------------------------------------------------------------------
// Kernel 2: center by spatial mean of y, L2-normalize each (b,n) vector over C,
// emit bf16. 256 threads = 4 waves, one wave per (b,n) row.
__global__ void k_norm(const float* __restrict__ fx, const float* __restrict__ fy,
                       const float* __restrict__ mean,
                       __hip_bfloat16* __restrict__ fxn, __hip_bfloat16* __restrict__ fyn)
{
    int bn = blockIdx.x * 4 + (threadIdx.x >> 6);   // 0 .. B*N-1
    int b = bn >> 12;
    int l = threadIdx.x & 63;
    const float* px = fx + (size_t)bn * Cc;
    const float* py = fy + (size_t)bn * Cc;
    const float* mp = mean + b * Cc;

    float m0 = mp[l]      * (1.f / Nn);
    float m1 = mp[l + 64] * (1.f / Nn);
    float x0 = px[l] - m0, x1 = px[l + 64] - m1;
    float y0 = py[l] - m0, y1 = py[l + 64] - m1;
    float sx = x0 * x0 + x1 * x1;
    float sy = y0 * y0 + y1 * y1;
    #pragma unroll
    for (int o = 32; o > 0; o >>= 1) {
        sx += __shfl_xor(sx, o);
        sy += __shfl_xor(sy, o);
    }
    float ix = 1.f / (sqrtf(sx) + EPSN);
    float iy = 1.f / (sqrtf(sy) + EPSN);
    fxn[(size_t)bn * Cc + l]      = __float2bfloat16(x0 * ix);
    fxn[(size_t)bn * Cc + l + 64] = __float2bfloat16(x1 * ix);
    fyn[(size_t)bn * Cc + l]      = __float2bfloat16(y0 * iy);
    fyn[(size_t)bn * Cc + l + 64] = __float2bfloat16(y1 * iy);
}

// ---------------------------------------------------------------------------
// MFMA core: per batch, S = X · Y^T  (M=N=4096, K=C=128).
// R6 structure (inner loop/registers identical to the no-spill R5):
//  - 512 blocks (1 co-residency round at 2 blocks/CU), each block = one
//    128-row A strip x EIGHT 128-row m-tiles (was 2). 4x MFMA work per block
//    against the same fixed overhead (A-DMA drain, prologue, epilogue), and a
//    32-step prefetch pipeline that stays in steady state.
//  - XCD-aware decode: xcd = bid&7 owns 2 (b,my) pairs -> per-XCD working set
//    (1 MB A + 2x256KB B panels x2) ~2.5 MB < 4 MB XCD-L2. B-panel reads become
//    L2-hits instead of L3 (previously every panel was pulled by all 8 XCDs).
//  - pmax/ssp: 4 slices (was 16).
//  - depth-1 B ping-pong (bbA/bbB) carried ACROSS mt iterations; last
//    iteration's prefetch clamped to pB0 (avoids OOB read past the batch).
//  - __launch_bounds__(256,2): cap 256, no spill (R5-verified, VGPR=128).
// PASS 1: per-row per-my max of dot -> pmax[my][b*N+row]
// PASS 2: prologue reduces pmax -> affine exp coeffs in LDS;
//         per-row per-my sum exp(fma(dot,c1,c0)) -> ssp[my][...]
template <int PASS>
__global__ __launch_bounds__(256, 2) void k_gemm(
    const ushort* __restrict__ fxn, const ushort* __restrict__ fyn,
    float* __restrict__ pmax, float* __restrict__ ssp)
{
    // union: sA (32 KB, staging + fragment reads) then sred (18 KB, epilogue)
    __shared__ __align__(16) char smem[128 * 128 * 2];
    ushort* sA   = (ushort*)smem;
    float*  sred = (float*)smem;
    __shared__ float sctv[256];         // 1 KB {c0,c1} per row

    const int tid  = threadIdx.x;
    const int lane = tid & 63;
    const int w    = tid >> 6;

    // XCD-aware decode: 512 blocks, bid&7 = XCD (round-robin dispatch).
    // Each XCD gets 2 (b,my) pairs and all 32 n-strips for them.
    const int bid  = blockIdx.x;
    const int xcd  = bid & 7;
    const int s_   = bid >> 3;            // 0..63
    const int pair = xcd * 2 + (s_ >> 5); // 0..15
    const int b    = pair >> 2;
    const int my   = pair & 3;            // m-range: (my*8 .. my*8+7) * 128
    const int n0   = (s_ & 31) * 128;

    const ushort* gA = fxn + (size_t)b * Nn * Cc;
    const ushort* gB = fyn + (size_t)b * Nn * Cc;

    // PASS 2 prologue: 4 max-partials -> {c0,c1}: arg(dot) = dot*t + (d-1)*t,
    // d = 1 - maxdot, t = 1/(HP*(d+eps)).
    if (PASS == 2 && tid < 128) {
        int row = b * Nn + n0 + tid;
        float g = -1e30f;
        #pragma unroll
        for (int z = 0; z < NSLC; ++z) g = fmaxf(g, pmax[(size_t)z * BN + row]);
        float d = 1.f - g;
        float t = 1.f / (HP * (d + EPSM));
        ((float2*)sctv)[tid] = (float2){(d - 1.f) * t, t};
    }

    // Stage A strip once (async DMA; chunk16 c of row r at slot c^(r&15)).
    #pragma unroll
    for (int inst = 0; inst < 8; ++inst) {
        int L0 = w * 512 + inst * 64;
        int L  = L0 + lane;
        int r = L >> 4, s = L & 15;
        int c = s ^ (r & 15);
        gload_lds16(gA + (size_t)(n0 + r) * Cc + c * 8, &sA[L0 * 8]);
    }

    const int l15 = lane & 15, q = lane >> 4;
    const int wy = w >> 1, wx = w & 1;     // wave's 64x64 quadrant

    // Per-lane B base for m-tile my*8.
    const ushort* pB0 = gB + (size_t)((my * 8) * 128 + wx * 64 + l15) * Cc + q * 8;

#define LOADB(buf, base, kt)                                                   \
    {                                                                          \
        buf[0] = *(const short8*)((base) + (size_t)0 * 16 * Cc + (kt) * 32);   \
        buf[1] = *(const short8*)((base) + (size_t)1 * 16 * Cc + (kt) * 32);   \
        buf[2] = *(const short8*)((base) + (size_t)2 * 16 * Cc + (kt) * 32);   \
        buf[3] = *(const short8*)((base) + (size_t)3 * 16 * Cc + (kt) * 32);   \
    }

#define DOKT(kt, buf)                                                          \
    {                                                                          \
        const int sw = (((kt) * 4 + q) ^ l15) * 8;                             \
        short8 a0 = *(const short8*)&sA[(wy * 64 +  0 + l15) * 128 + sw];      \
        short8 a1 = *(const short8*)&sA[(wy * 64 + 16 + l15) * 128 + sw];      \
        short8 a2 = *(const short8*)&sA[(wy * 64 + 32 + l15) * 128 + sw];      \
        short8 a3 = *(const short8*)&sA[(wy * 64 + 48 + l15) * 128 + sw];      \
        acc[0][0] = __builtin_amdgcn_mfma_f32_16x16x32_bf16(a0, buf[0], acc[0][0], 0, 0, 0); \
        acc[0][1] = __builtin_amdgcn_mfma_f32_16x16x32_bf16(a0, buf[1], acc[0][1], 0, 0, 0); \
        acc[0][2] = __builtin_amdgcn_mfma_f32_16x16x32_bf16(a0, buf[2], acc[0][2], 0, 0, 0); \
        acc[0][3] = __builtin_amdgcn_mfma_f32_16x16x32_bf16(a0, buf[3], acc[0][3], 0, 0, 0); \
        acc[1][0] = __builtin_amdgcn_mfma_f32_16x16x32_bf16(a1, buf[0], acc[1][0], 0, 0, 0); \
        acc[1][1] = __builtin_amdgcn_mfma_f32_16x16x32_bf16(a1, buf[1], acc[1][1], 0, 0, 0); \
        acc[1][2] = __builtin_amdgcn_mfma_f32_16x16x32_bf16(a1, buf[2], acc[1][2], 0, 0, 0); \
        acc[1][3] = __builtin_amdgcn_mfma_f32_16x16x32_bf16(a1, buf[3], acc[1][3], 0, 0, 0); \
        acc[2][0] = __builtin_amdgcn_mfma_f32_16x16x32_bf16(a2, buf[0], acc[2][0], 0, 0, 0); \
        acc[2][1] = __builtin_amdgcn_mfma_f32_16x16x32_bf16(a2, buf[1], acc[2][1], 0, 0, 0); \
        acc[2][2] = __builtin_amdgcn_mfma_f32_16x16x32_bf16(a2, buf[2], acc[2][2], 0, 0, 0); \
        acc[2][3] = __builtin_amdgcn_mfma_f32_16x16x32_bf16(a2, buf[3], acc[2][3], 0, 0, 0); \
        acc[3][0] = __builtin_amdgcn_mfma_f32_16x16x32_bf16(a3, buf[0], acc[3][0], 0, 0, 0); \
        acc[3][1] = __builtin_amdgcn_mfma_f32_16x16x32_bf16(a3, buf[1], acc[3][1], 0, 0, 0); \
        acc[3][2] = __builtin_amdgcn_mfma_f32_16x16x32_bf16(a3, buf[2], acc[3][2], 0, 0, 0); \
        acc[3][3] = __builtin_amdgcn_mfma_f32_16x16x32_bf16(a3, buf[3], acc[3][3], 0, 0, 0); \
    }

// Fold current acc into vpart (regs only), then reset acc.
// C/D layout: col = lane&15, row = (lane>>4)*4 + reg  [m89-verified]
#define FOLD()                                                                 \
    {                                                                          \
        _Pragma("unroll")                                                      \
        for (int i = 0; i < 4; ++i) {                                          \
            _Pragma("unroll")                                                  \
            for (int r = 0; r < 4; ++r) {                                      \
                if (PASS == 1) {                                               \
                    float v = fmaxf(fmaxf(acc[i][0][r], acc[i][1][r]),         \
                                    fmaxf(acc[i][2][r], acc[i][3][r]));        \
                    vpart[i][r] = fmaxf(vpart[i][r], v);                       \
                } else {                                                       \
                    int row = wy * 64 + i * 16 + q * 4 + r;                    \
                    float2 cc = ((const float2*)sctv)[row];                    \
                    vpart[i][r] += __expf(fmaf(acc[i][0][r], cc.y, cc.x))      \
                                 + __expf(fmaf(acc[i][1][r], cc.y, cc.x))      \
                                 + __expf(fmaf(acc[i][2][r], cc.y, cc.x))      \
                                 + __expf(fmaf(acc[i][3][r], cc.y, cc.x));     \
                }                                                              \
            }                                                                  \
            _Pragma("unroll")                                                  \
            for (int j = 0; j < 4; ++j)                                        \
                acc[i][j] = (f32x4){0.f, 0.f, 0.f, 0.f};                       \
        }                                                                      \
    }

    short8 bbA[4], bbB[4];
    LOADB(bbA, pB0, 0);        // rides under the A-DMA drain
    __syncthreads();           // drains DMA (and bbA); sA + sctv visible

    f32x4 acc[4][4];
    #pragma unroll
    for (int i = 0; i < 4; ++i)
        #pragma unroll
        for (int j = 0; j < 4; ++j)
            acc[i][j] = (f32x4){0.f, 0.f, 0.f, 0.f};

    float vpart[4][4];
    #pragma unroll
    for (int i = 0; i < 4; ++i)
        #pragma unroll
        for (int r = 0; r < 4; ++r)
            vpart[i][r] = (PASS == 1) ? -1e30f : 0.f;

    // 8 m-tiles; depth-1 B prefetch ping-pongs bbA/bbB across iterations.
    const ushort* pB = pB0;
    #pragma unroll 1
    for (int mt = 0; mt < 8; ++mt) {
        // next-mt prefetch base; clamp on last iteration (avoid OOB)
        const ushort* pBn = (mt == 7) ? pB0 : (pB + (size_t)128 * Cc);
        LOADB(bbB, pB, 1);  DOKT(0, bbA);
        LOADB(bbA, pB, 2);  DOKT(1, bbB);
        LOADB(bbB, pB, 3);  DOKT(2, bbA);
        LOADB(bbA, pBn, 0); DOKT(3, bbB);
        FOLD();                                // fold m-tile into vpart
        pB = pBn;
    }

#undef LOADB
#undef DOKT
#undef FOLD

    // Single epilogue: all waves done reading sA -> reuse as sred.
    __syncthreads();
    #pragma unroll
    for (int i = 0; i < 4; ++i)
        #pragma unroll
        for (int r = 0; r < 4; ++r) {
            int row = wy * 64 + i * 16 + q * 4 + r;
            sred[row * 36 + wx * 16 + l15] = vpart[i][r];
        }
    __syncthreads();   // sred complete
    if (tid < 128) {
        const float4* p = (const float4*)&sred[tid * 36];
        float4 v0 = p[0], v1 = p[1], v2 = p[2], v3 = p[3];
        float4 v4 = p[4], v5 = p[5], v6 = p[6], v7 = p[7];
        float v;
        if (PASS == 1) {
            float4 m01 = (float4){fmaxf(v0.x, v1.x), fmaxf(v0.y, v1.y),
                                  fmaxf(v0.z, v1.z), fmaxf(v0.w, v1.w)};
            float4 m23 = (float4){fmaxf(v2.x, v3.x), fmaxf(v2.y, v3.y),
                                  fmaxf(v2.z, v3.z), fmaxf(v2.w, v3.w)};
            float4 m45 = (float4){fmaxf(v4.x, v5.x), fmaxf(v4.y, v5.y),
                                  fmaxf(v4.z, v5.z), fmaxf(v4.w, v5.w)};
            float4 m67 = (float4){fmaxf(v6.x, v7.x), fmaxf(v6.y, v7.y),
                                  fmaxf(v6.z, v7.z), fmaxf(v6.w, v7.w)};
            float4 ma = (float4){fmaxf(m01.x, m23.x), fmaxf(m01.y, m23.y),
                                 fmaxf(m01.z, m23.z), fmaxf(m01.w, m23.w)};
            float4 mb = (float4){fmaxf(m45.x, m67.x), fmaxf(m45.y, m67.y),
                                 fmaxf(m45.z, m67.z), fmaxf(m45.w, m67.w)};
            v = fmaxf(fmaxf(fmaxf(ma.x, mb.x), fmaxf(ma.y, mb.y)),
                      fmaxf(fmaxf(ma.z, mb.z), fmaxf(ma.w, mb.w)));
        } else {
            float4 s01 = (float4){v0.x + v1.x, v0.y + v1.y,
                                  v0.z + v1.z, v0.w + v1.w};
            float4 s23 = (float4){v2.x + v3.x, v2.y + v3.y,
                                  v2.z + v3.z, v2.w + v3.w};
            float4 s45 = (float4){v4.x + v5.x, v4.y + v5.y,
                                  v4.z + v5.z, v4.w + v5.w};
            float4 s67 = (float4){v6.x + v7.x, v6.y + v7.y,
                                  v6.z + v7.z, v6.w + v7.w};
            v = (s01.x + s23.x) + (s01.y + s23.y)
              + (s01.z + s23.z) + (s01.w + s23.w)
              + (s45.x + s67.x) + (s45.y + s67.y)
              + (s45.z + s67.z) + (s45.w + s67.w);
        }
        float* dst = (PASS == 1) ? pmax : ssp;
        dst[(size_t)my * BN + b * Nn + n0 + tid] = v;
    }
}

// ---------------------------------------------------------------------------
// Stage 1 of final reduction: per-row 1/s, block-sum, atomicAdd per batch.
__global__ void k_partial(const float* __restrict__ ssp, float* __restrict__ acc)
{
    int i = blockIdx.x * 256 + threadIdx.x;   // 0 .. B*N-1 (block spans one batch)
    float t = 0.f;
    #pragma unroll
    for (int z = 0; z < NSLC; ++z) t += ssp[(size_t)z * BN + i];
    float s = 1.f / t;
    #pragma unroll
    for (int o = 32; o > 0; o >>= 1) s += __shfl_xor(s, o);
    __shared__ float red[4];
    if ((threadIdx.x & 63) == 0) red[threadIdx.x >> 6] = s;
    __syncthreads();
    if (threadIdx.x == 0)
        atomicAdd(&acc[i >> 12], red[0] + red[1] + red[2] + red[3]);
}

__global__ void k_out(const float* __restrict__ acc, float* __restrict__ out)
{
    int b = threadIdx.x;
    if (b < Bb) out[b] = -logf(acc[b] * (1.f / Nn));
}

// ---------------------------------------------------------------------------
extern "C" void kernel_launch(void* const* d_in, const int* in_sizes, int n_in,
                              void* d_out, int out_size, void* d_ws, size_t ws_size,
                              hipStream_t stream)
{
    const float* fx = (const float*)d_in[0];
    const float* fy = (const float*)d_in[1];
    float* out = (float*)d_out;
    float* ws  = (float*)d_ws;

    float* mean = ws + OFF_MEAN;
    float* acc  = ws + OFF_ACC;
    float* pmax = ws + OFF_PMAX;
    float* ssp  = ws + OFF_SSP;
    __hip_bfloat16* fxn = (__hip_bfloat16*)(ws + OFF_FXN);
    __hip_bfloat16* fyn = (__hip_bfloat16*)(ws + OFF_FYN);

    // zero the atomicAdd accumulators (mean @0..511, acc @512..515)
    hipMemsetAsync(ws, 0, 516 * sizeof(float), stream);

    k_mean<<<dim3(Bb * 32), dim3(128), 0, stream>>>(fy, mean);
    k_norm<<<dim3(Bb * Nn / 4), dim3(256), 0, stream>>>(fx, fy, mean, fxn, fyn);

    // 512 blocks = one co-residency round at 2 blocks/CU; 8 m-tiles each
    dim3 gg(512);
    k_gemm<1><<<gg, dim3(256), 0, stream>>>((const ushort*)fxn, (const ushort*)fyn,
                                            pmax, nullptr);
    k_gemm<2><<<gg, dim3(256), 0, stream>>>((const ushort*)fxn, (const ushort*)fyn,
                                            pmax, ssp);
    k_partial<<<dim3(BN / 256), dim3(256), 0, stream>>>(ssp, acc);
    k_out<<<dim3(1), dim3(64), 0, stream>>>(acc, out);
}